// Round 8
// baseline (479.910 us; speedup 1.0000x reference)
//
#include <hip/hip_runtime.h>

// B=2048 patients, K=4, PAIRS=6 -> P=12288 pairs, C=1280, K_gemm=2560
// ii = [0,0,0,1,1,2], jj = [1,2,3,2,3,3]
// masks: jax threefry2x32 key(0,42), (5,12288,1280), partitionable scheme:
//   bits[i] = o0^o1, (o0,o1) = tf2x32(key,(0,i)); dropout-keep == MSB==0

typedef __attribute__((ext_vector_type(8))) short short8;
typedef __attribute__((ext_vector_type(4))) float f32x4;

#define PLANE 15728640u      // P*C
#define KS2   (0x1BD11BDAu ^ 42u)

__device__ __forceinline__ unsigned short f2bf(float f) {
  unsigned int u = __builtin_bit_cast(unsigned int, f);
  u = (u + 0x7FFFu + ((u >> 16) & 1u)) >> 16;   // RNE
  return (unsigned short)u;
}
__device__ __forceinline__ float bf2f(unsigned short h) {
  unsigned int u = ((unsigned int)h) << 16;
  return __builtin_bit_cast(float, u);
}

// ---------------- prep: conv_x + conv_w ----------------
__global__ __launch_bounds__(256) void prep(
    const float* __restrict__ x, unsigned short* __restrict__ xb,
    const float* __restrict__ Wc, unsigned short* __restrict__ Wb) {
  const int bid = blockIdx.x;
  const int t = threadIdx.x;
  if (bid < 10240) {                      // x fp32 -> bf16 (4/thread)
    const int i = (bid * 256 + t) * 4;
    float4 v = *(const float4*)(x + i);
    ushort4 o;
    o.x = f2bf(v.x); o.y = f2bf(v.y); o.z = f2bf(v.z); o.w = f2bf(v.w);
    *(ushort4*)(xb + i) = o;
  } else {                                // Wc (C,C,2) -> W' [1280][2560] bf16
    const int idx = (bid - 10240) * 256 + t;
    const int n = idx / 2560;
    const int k = idx - n * 2560;
    const int side = (k >= 1280) ? 1 : 0;
    const int cin = k - side * 1280;
    Wb[idx] = f2bf(Wc[n * 2560 + cin * 2 + side]);
  }
}

// ---------------- threefry2x32-20 MSB, key=(0,42), counter hi = 0 ----------
// Key injections fused into the following round's add. Verified equivalent to
// the R5-passing ladder form (ks=[0,42,KS2]; inj_i: x0+=ks[i%3], x1+=ks[(i+1)%3]+i).
__device__ __forceinline__ unsigned int rotl(unsigned int x, int r) {
  return __builtin_amdgcn_alignbit(x, x, 32 - r);
}
__device__ __forceinline__ unsigned int tf_msb(unsigned int c) {
  // c = counter_lo + 42 (initial key add folded in); counter_hi = 0
  unsigned int x0 = c;
  unsigned int x1 = rotl(c, 13) ^ c;                       // round 1
  x0 += x1; x1 = rotl(x1, 15) ^ x0;
  x0 += x1; x1 = rotl(x1, 26) ^ x0;
  x0 += x1; x1 = rotl(x1, 6)  ^ x0;
  unsigned int t;
  t = x1 + (KS2 + 1u); x0 = x0 + t + 42u; x1 = rotl(t, 17) ^ x0;   // inj1+r5
  x0 += x1; x1 = rotl(x1, 29) ^ x0;
  x0 += x1; x1 = rotl(x1, 16) ^ x0;
  x0 += x1; x1 = rotl(x1, 24) ^ x0;
  t = x1 + 2u; x0 = x0 + t + KS2; x1 = rotl(t, 13) ^ x0;           // inj2+r9
  x0 += x1; x1 = rotl(x1, 15) ^ x0;
  x0 += x1; x1 = rotl(x1, 26) ^ x0;
  x0 += x1; x1 = rotl(x1, 6)  ^ x0;
  t = x1 + 45u; x0 = x0 + t; x1 = rotl(t, 17) ^ x0;                // inj3+r13
  x0 += x1; x1 = rotl(x1, 29) ^ x0;
  x0 += x1; x1 = rotl(x1, 16) ^ x0;
  x0 += x1; x1 = rotl(x1, 24) ^ x0;
  t = x1 + (KS2 + 4u); x0 = x0 + t + 42u; x1 = rotl(t, 13) ^ x0;   // inj4+r17
  x0 += x1; x1 = rotl(x1, 15) ^ x0;
  x0 += x1; x1 = rotl(x1, 26) ^ x0;
  x0 += x1; x1 = rotl(x1, 6)  ^ x0;
  return ((x0 + KS2) ^ (x1 + 5u)) >> 31;                           // inj5+fold
}

// ---------------- mixed kernel: GEMM-tile blocks + barrier-free RNG blocks ----
// grid 2048 = 8 banks of 256; even banks -> GEMM (ids 0..959, writes Xc),
// odd banks -> RNG (ids 0..959, packs keep-counts into S nibbles).
// Banked interleave => each CU co-hosts both roles; RNG waves saturate the
// 4-cyc int-VALU pipe through GEMM barrier stalls (m114 co-schedule).
#define GL_LDS(g, l) __builtin_amdgcn_global_load_lds( \
    (const __attribute__((address_space(1))) unsigned int*)(g), \
    (__attribute__((address_space(3))) unsigned int*)(l), 16, 0, 0)

__global__ __launch_bounds__(256) void mixed(
    const unsigned short* __restrict__ Xb,   // [8192][1280] bf16
    const unsigned short* __restrict__ Wb,   // [1280][2560] bf16
    const float* __restrict__ bc,
    unsigned short* __restrict__ Xc,         // [12288][1280] bf16
    unsigned int* __restrict__ Spk)          // packed keep-counts, 4b/cell, LINEAR
{
  const int bid = blockIdx.x;
  const int rnd = bid >> 8;
  const int slot = bid & 255;
  const int id = (rnd >> 1) * 256 + slot;
  const int t = threadIdx.x;
  if (id >= 960) return;

  if (rnd & 1) {
    // ====== RNG role: dword D = id*2048 + g*256 + t holds cells D*8..D*8+7 ====
    // (linear layout for combine; writes coalesced across t at fixed g)
    unsigned int* const Sp = Spk + id * 2048 + t;
    for (int g = 0; g < 8; ++g) {
      const unsigned int bg =
          (unsigned int)(id * 2048 + g * 256 + t) * 8u + 42u;
      unsigned int zacc = 0;
#pragma unroll
      for (int sub = 0; sub < 8; ++sub) {
        const unsigned int b = bg + (unsigned int)sub;
        const unsigned int z5 = tf_msb(b) + tf_msb(b + PLANE) +
                                tf_msb(b + 2u * PLANE) + tf_msb(b + 3u * PLANE) +
                                tf_msb(b + 4u * PLANE);
        zacc |= z5 << (4 * sub);
      }
      Sp[g * 256] = zacc;
    }
    return;
  }

  // ================= GEMM role: m97-structure 128x128 tile ================
  __shared__ unsigned short sA[128 * 32];
  __shared__ unsigned short sB[128 * 32];
  const int mblk = id % 96;
  const int nblk = id / 96;
  const int p0 = mblk * 128, n0 = nblk * 128;
  const int lane = t & 63, w = t >> 6;
  const int wr = w >> 1, wc = w & 1;
  const int q = lane & 3;
  const int rl = lane >> 2;
  const int mrow = lane & 15;
  const int koff = (lane >> 4) * 8;

  int rA[2], rB[2], rN[2];
#pragma unroll
  for (int i = 0; i < 2; i++) {
    const int row = w * 32 + i * 16 + rl;
    const int pg = p0 + row;
    const int bA = pg / 6, pr = pg - bA * 6;
    rA[i] = bA * 4 + ((0x211000 >> (4 * pr)) & 7);   // ii side (k<1280)
    rB[i] = bA * 4 + ((0x332321 >> (4 * pr)) & 7);   // jj side (k>=1280)
    rN[i] = n0 + row;
  }
  unsigned short* const ldsA0 = sA + (w * 32 + 0) * 32;
  unsigned short* const ldsA1 = sA + (w * 32 + 16) * 32;
  unsigned short* const ldsB0 = sB + (w * 32 + 0) * 32;
  unsigned short* const ldsB1 = sB + (w * 32 + 16) * 32;
  const unsigned short* const gA0s0 = Xb + rA[0] * 1280 + q * 8;
  const unsigned short* const gA1s0 = Xb + rA[1] * 1280 + q * 8;
  const unsigned short* const gA0s1 = Xb + rB[0] * 1280 + q * 8;
  const unsigned short* const gA1s1 = Xb + rB[1] * 1280 + q * 8;
  const unsigned short* const gB0 = Wb + rN[0] * 2560 + q * 8;
  const unsigned short* const gB1 = Wb + rN[1] * 2560 + q * 8;

  f32x4 acc[4][4];
#pragma unroll
  for (int i = 0; i < 4; i++)
#pragma unroll
    for (int j = 0; j < 4; j++) acc[i][j] = (f32x4){0.f, 0.f, 0.f, 0.f};

#define KSTEP(Ga0, Ga1, kb, kg)                                              \
  {                                                                          \
    __syncthreads();                                                         \
    GL_LDS(Ga0 + (kb), ldsA0);                                               \
    GL_LDS(Ga1 + (kb), ldsA1);                                               \
    GL_LDS(gB0 + (kg), ldsB0);                                               \
    GL_LDS(gB1 + (kg), ldsB1);                                               \
    __syncthreads();                                                         \
    short8 af[4], bfr[4];                                                    \
    _Pragma("unroll")                                                        \
    for (int i = 0; i < 4; i++)                                              \
      af[i] = *(const short8*)(sA + (wr * 64 + i * 16 + mrow) * 32 + koff);  \
    _Pragma("unroll")                                                        \
    for (int j = 0; j < 4; j++)                                              \
      bfr[j] = *(const short8*)(sB + (wc * 64 + j * 16 + mrow) * 32 + koff); \
    _Pragma("unroll")                                                        \
    for (int i = 0; i < 4; i++)                                              \
      _Pragma("unroll")                                                      \
      for (int j = 0; j < 4; j++)                                            \
        acc[i][j] = __builtin_amdgcn_mfma_f32_16x16x32_bf16(af[i], bfr[j],   \
                                                            acc[i][j], 0, 0, 0); \
  }

  for (int k0 = 0; k0 < 1280; k0 += 32) KSTEP(gA0s0, gA1s0, k0, k0);
  for (int k0 = 1280; k0 < 2560; k0 += 32) KSTEP(gA0s1, gA1s1, k0 - 1280, k0);
#undef KSTEP

  // epilogue: D layout col=lane&15, row=(lane>>4)*4+reg [m89/m91]
  const int mq = (lane >> 4) * 4;
  const int nn = lane & 15;
#pragma unroll
  for (int j = 0; j < 4; j++) {
    const int n = n0 + wc * 64 + j * 16 + nn;
    const float bcv = bc[n];
#pragma unroll
    for (int i = 0; i < 4; i++) {
      const int prow = p0 + wr * 64 + i * 16 + mq;
#pragma unroll
      for (int rg = 0; rg < 4; rg++) {
        float v = acc[i][j][rg] + bcv;
        v = v > 0.f ? v : 0.f;
        Xc[(prow + rg) * 1280 + n] = f2bf(v);
      }
    }
  }
}

// ---------------- combine: block per patient, no atomics ----------------
// out[pat][h] = b_h + (1/15) * sum_{cells} Xc * (5 - z) * W_h
__global__ __launch_bounds__(256) void combine(
    const unsigned short* __restrict__ Xc,
    const unsigned int* __restrict__ Spk,
    const float* __restrict__ W0, const float* __restrict__ W1,
    const float* __restrict__ W2,
    const float* __restrict__ b0, const float* __restrict__ b1,
    const float* __restrict__ b2, float* __restrict__ out)
{
  const int pat = blockIdx.x;
  const int t = threadIdx.x;
  __shared__ float sW[3 * 1280];
  for (int i = t; i < 960; i += 256) {
    const float4 v = (i < 320) ? ((const float4*)W0)[i]
                   : (i < 640) ? ((const float4*)W1)[i - 320]
                               : ((const float4*)W2)[i - 640];
    ((float4*)sW)[i] = v;
  }
  __syncthreads();

  float s0 = 0.f, s1 = 0.f, s2 = 0.f;
  if (t < 240) {
    // thread covers 32 consecutive cells: f0 = pat*7680 + t*32, c0 = f0 % 1280
    const int f0 = pat * 7680 + t * 32;
    const int c0 = (t * 32) % 1280;
    const uint4 sd = ((const uint4*)Spk)[pat * 240 + t];
    const unsigned int dws[4] = {sd.x, sd.y, sd.z, sd.w};
    const uint4* const xp = (const uint4*)(Xc + f0);
#pragma unroll
    for (int d = 0; d < 4; d++) {
      const uint4 xv = xp[d];
      const unsigned int xs[4] = {xv.x, xv.y, xv.z, xv.w};
      const unsigned int dw = dws[d];
#pragma unroll
      for (int k = 0; k < 8; k++) {
        const unsigned short h = (unsigned short)(xs[k >> 1] >> ((k & 1) * 16));
        const float S = (float)(5 - (int)((dw >> (4 * k)) & 7u));
        const float tx = bf2f(h) * S;
        const int c = c0 + d * 8 + k;
        s0 += tx * sW[c]; s1 += tx * sW[1280 + c]; s2 += tx * sW[2560 + c];
      }
    }
  }

#pragma unroll
  for (int off = 32; off > 0; off >>= 1) {
    s0 += __shfl_xor(s0, off); s1 += __shfl_xor(s1, off); s2 += __shfl_xor(s2, off);
  }
  __shared__ float red[4][3];
  const int lane = t & 63, w = t >> 6;
  if (lane == 0) { red[w][0] = s0; red[w][1] = s1; red[w][2] = s2; }
  __syncthreads();
  if (t == 0) {
    const float r0 = red[0][0] + red[1][0] + red[2][0] + red[3][0];
    const float r1 = red[0][1] + red[1][1] + red[2][1] + red[3][1];
    const float r2 = red[0][2] + red[1][2] + red[2][2] + red[3][2];
    out[pat * 3 + 0] = b0[0] + r0 * (1.0f / 15.0f);
    out[pat * 3 + 1] = b1[0] + r1 * (1.0f / 15.0f);
    out[pat * 3 + 2] = b2[0] + r2 * (1.0f / 15.0f);
  }
}

extern "C" void kernel_launch(void* const* d_in, const int* in_sizes, int n_in,
                              void* d_out, int out_size, void* d_ws, size_t ws_size,
                              hipStream_t stream) {
  const float* x  = (const float*)d_in[0];
  // d_in[1] = ids2 (int32): repeat(arange(B),6) -> hardcoded pat = p/6 mapping
  const float* Wc = (const float*)d_in[2];
  const float* bc = (const float*)d_in[3];
  const float* W0 = (const float*)d_in[4];
  const float* b0 = (const float*)d_in[5];
  const float* W1 = (const float*)d_in[6];
  const float* b1 = (const float*)d_in[7];
  const float* W2 = (const float*)d_in[8];
  const float* b2 = (const float*)d_in[9];
  float* out = (float*)d_out;

  char* ws = (char*)d_ws;
  unsigned short* xb  = (unsigned short*)ws;                      // 20,971,520 B
  unsigned short* Wb  = (unsigned short*)(ws + 20971520);         //  6,553,600 B
  unsigned short* Xc  = (unsigned short*)(ws + 27525120);         // 31,457,280 B
  unsigned int*   Spk = (unsigned int*)(ws + 58982400);           //  7,864,320 B

  prep<<<23040, 256, 0, stream>>>(x, xb, Wc, Wb);
  mixed<<<2048, 256, 0, stream>>>(xb, Wb, bc, Xc, Spk);
  combine<<<2048, 256, 0, stream>>>(Xc, Spk, W0, W1, W2, b0, b1, b2, out);
}

// Round 9
// 314.043 us; speedup vs baseline: 1.5282x; 1.5282x over previous
//
#include <hip/hip_runtime.h>

// B=2048 patients, K=4, PAIRS=6 -> P=12288 pairs, C=1280, K_gemm=2560
// ii = [0,0,0,1,1,2], jj = [1,2,3,2,3,3]
// masks: jax threefry2x32 key(0,42), (5,12288,1280), partitionable scheme:
//   bits[i] = o0^o1, (o0,o1) = tf2x32(key,(0,i)); dropout-keep == MSB==0

typedef __attribute__((ext_vector_type(8))) short short8;
typedef __attribute__((ext_vector_type(4))) float f32x4;

#define PLANE 15728640u      // P*C
#define KS2   (0x1BD11BDAu ^ 42u)

__device__ __forceinline__ unsigned short f2bf(float f) {
  unsigned int u = __builtin_bit_cast(unsigned int, f);
  u = (u + 0x7FFFu + ((u >> 16) & 1u)) >> 16;   // RNE
  return (unsigned short)u;
}

// ---------------- prep: conv_x + conv_w + init_out ----------------
__global__ __launch_bounds__(256) void prep(
    const float* __restrict__ x, unsigned short* __restrict__ xb,
    const float* __restrict__ Wc, unsigned short* __restrict__ Wb,
    const float* __restrict__ b0, const float* __restrict__ b1,
    const float* __restrict__ b2, float* __restrict__ out) {
  const int bid = blockIdx.x;
  const int t = threadIdx.x;
  if (bid < 10240) {                      // x fp32 -> bf16 (4/thread)
    const int i = (bid * 256 + t) * 4;
    float4 v = *(const float4*)(x + i);
    ushort4 o;
    o.x = f2bf(v.x); o.y = f2bf(v.y); o.z = f2bf(v.z); o.w = f2bf(v.w);
    *(ushort4*)(xb + i) = o;
  } else if (bid < 23040) {               // Wc (C,C,2) -> W' [1280][2560] bf16
    const int idx = (bid - 10240) * 256 + t;
    const int n = idx / 2560;
    const int k = idx - n * 2560;
    const int side = (k >= 1280) ? 1 : 0;
    const int cin = k - side * 1280;
    Wb[idx] = f2bf(Wc[n * 2560 + cin * 2 + side]);
  } else {                                // out[b][h] = bias_h
    const int i = (bid - 23040) * 256 + t;
    if (i < 2048 * 3) {
      const int h = i % 3;
      out[i] = (h == 0) ? b0[0] : ((h == 1) ? b1[0] : b2[0]);
    }
  }
}

// ---------------- threefry2x32-20 MSB, key=(0,42), counter hi = 0 ----------
__device__ __forceinline__ unsigned int rotl(unsigned int x, int r) {
  return __builtin_amdgcn_alignbit(x, x, 32 - r);
}
__device__ __forceinline__ unsigned int tf_msb(unsigned int c) {
  // c = counter_lo + 42 (initial key add folded in); counter_hi = 0
  unsigned int x0 = c;
  unsigned int x1 = rotl(c, 13) ^ c;                       // round 1
  x0 += x1; x1 = rotl(x1, 15) ^ x0;
  x0 += x1; x1 = rotl(x1, 26) ^ x0;
  x0 += x1; x1 = rotl(x1, 6)  ^ x0;
  unsigned int t;
  t = x1 + (KS2 + 1u); x0 = x0 + t + 42u; x1 = rotl(t, 17) ^ x0;   // inj1+r5
  x0 += x1; x1 = rotl(x1, 29) ^ x0;
  x0 += x1; x1 = rotl(x1, 16) ^ x0;
  x0 += x1; x1 = rotl(x1, 24) ^ x0;
  t = x1 + 2u; x0 = x0 + t + KS2; x1 = rotl(t, 13) ^ x0;           // inj2+r9
  x0 += x1; x1 = rotl(x1, 15) ^ x0;
  x0 += x1; x1 = rotl(x1, 26) ^ x0;
  x0 += x1; x1 = rotl(x1, 6)  ^ x0;
  t = x1 + 45u; x0 = x0 + t; x1 = rotl(t, 17) ^ x0;                // inj3+r13
  x0 += x1; x1 = rotl(x1, 29) ^ x0;
  x0 += x1; x1 = rotl(x1, 16) ^ x0;
  x0 += x1; x1 = rotl(x1, 24) ^ x0;
  t = x1 + (KS2 + 4u); x0 = x0 + t + 42u; x1 = rotl(t, 13) ^ x0;   // inj4+r17
  x0 += x1; x1 = rotl(x1, 15) ^ x0;
  x0 += x1; x1 = rotl(x1, 26) ^ x0;
  x0 += x1; x1 = rotl(x1, 6)  ^ x0;
  return ((x0 + KS2) ^ (x1 + 5u)) >> 31;                           // inj5+fold
}

// ---------------- fused kernel: 128x64-tile GEMM(+relu) + in-loop RNG + dot ----
// Grid 1920 (96 m x 20 n) -> ~5 blocks/CU resident: other blocks' RNG issue
// fills each wave's barrier-drain gaps (R5 was grid-limited at 3.75 waves/SIMD).
#define GL_LDS(g, l) __builtin_amdgcn_global_load_lds( \
    (const __attribute__((address_space(1))) unsigned int*)(g), \
    (__attribute__((address_space(3))) unsigned int*)(l), 16, 0, 0)

__global__ __launch_bounds__(256) void gemm_relu_dot(
    const unsigned short* __restrict__ Xb,   // [8192][1280] bf16
    const unsigned short* __restrict__ Wb,   // [1280][2560] bf16
    const float* __restrict__ bc,
    const float* __restrict__ W0, const float* __restrict__ W1,
    const float* __restrict__ W2, float* __restrict__ out)
{
  __shared__ unsigned short sA[128 * 32];      // 8 KB
  __shared__ unsigned short sB[64 * 32];       // 4 KB
  __shared__ unsigned int zLDS[4 * 256];       // 4 KB, [chunk][thread]
  __shared__ float rowsumA[128 * 3];           // wc=0 half (cols 0..31)
  __shared__ float rowsumB[128 * 3];           // wc=1 half (cols 32..63)

  const int t = threadIdx.x;
  const int id = blockIdx.x;
  const int mblk = id % 96;
  const int nblk = id / 96;
  const int p0 = mblk * 128, n0 = nblk * 64;
  const int lane = t & 63, w = t >> 6;
  const int wr = w >> 1, wc = w & 1;           // wave grid: 2(M) x 2(N)
  const int q = lane & 3;
  const int rl = lane >> 2;
  const int mrow = lane & 15;
  const int koff = (lane >> 4) * 8;
  const int mq = (lane >> 4) * 4;              // C/D row quad [m89/m91]
  const int nn = lane & 15;                    // C/D col

  // A staging: wave w stages rows [w*32, w*32+32), 2 calls of 16 rows
  int rA[2], rB[2];
#pragma unroll
  for (int i = 0; i < 2; i++) {
    const int row = w * 32 + i * 16 + rl;
    const int pg = p0 + row;
    const int bA = pg / 6, pr = pg - bA * 6;
    rA[i] = bA * 4 + ((0x211000 >> (4 * pr)) & 7);   // ii side (k<1280)
    rB[i] = bA * 4 + ((0x332321 >> (4 * pr)) & 7);   // jj side (k>=1280)
  }
  // B staging: wave w stages rows [w*16, w*16+16), 1 call
  const int rN = n0 + w * 16 + rl;

  unsigned short* const ldsA0 = sA + (w * 32 + 0) * 32;
  unsigned short* const ldsA1 = sA + (w * 32 + 16) * 32;
  unsigned short* const ldsB0 = sB + (w * 16) * 32;
  const unsigned short* const gA0s0 = Xb + rA[0] * 1280 + q * 8;
  const unsigned short* const gA1s0 = Xb + rA[1] * 1280 + q * 8;
  const unsigned short* const gA0s1 = Xb + rB[0] * 1280 + q * 8;
  const unsigned short* const gA1s1 = Xb + rB[1] * 1280 + q * 8;
  const unsigned short* const gB0 = Wb + rN * 2560 + q * 8;

  f32x4 acc[4][2];
#pragma unroll
  for (int i = 0; i < 4; i++)
#pragma unroll
    for (int j = 0; j < 2; j++) acc[i][j] = (f32x4){0.f, 0.f, 0.f, 0.f};

  // RNG base: cell idx (0..31): i=idx>>3, j=(idx>>2)&1, rg=idx&3
  // counter = (p0+wr*64+i*16+mq+rg)*1280 + n0+wc*32+j*16+nn + 42
  const unsigned int tb =
      (unsigned int)((p0 + wr * 64 + mq) * 1280 + n0 + wc * 32 + nn) + 42u;

#define KSTEP(Ga0, Ga1, kb, kg)                                              \
  {                                                                          \
    __syncthreads();                                                         \
    GL_LDS(Ga0 + (kb), ldsA0);                                               \
    GL_LDS(Ga1 + (kb), ldsA1);                                               \
    GL_LDS(gB0 + (kg), ldsB0);                                               \
    __syncthreads();                                                         \
    short8 af[4], bfr[2];                                                    \
    _Pragma("unroll")                                                        \
    for (int i = 0; i < 4; i++)                                              \
      af[i] = *(const short8*)(sA + (wr * 64 + i * 16 + mrow) * 32 + koff);  \
    _Pragma("unroll")                                                        \
    for (int j = 0; j < 2; j++)                                              \
      bfr[j] = *(const short8*)(sB + (wc * 32 + j * 16 + mrow) * 32 + koff); \
    _Pragma("unroll")                                                        \
    for (int i = 0; i < 4; i++)                                              \
      _Pragma("unroll")                                                      \
      for (int j = 0; j < 2; j++)                                            \
        acc[i][j] = __builtin_amdgcn_mfma_f32_16x16x32_bf16(af[i], bfr[j],   \
                                                            acc[i][j], 0, 0, 0); \
  }

#define CELL_RNG(it)                                                         \
  {                                                                          \
    const int idx = (it);                                                    \
    const unsigned int b = tb +                                              \
        (unsigned int)((((idx >> 3) * 16 + (idx & 3)) * 1280) +              \
                       (((idx >> 2) & 1) * 16));                             \
    const unsigned int z5 = tf_msb(b) + tf_msb(b + PLANE) +                  \
                            tf_msb(b + 2u * PLANE) + tf_msb(b + 3u * PLANE) +\
                            tf_msb(b + 4u * PLANE);                          \
    zacc |= z5 << (4 * sub);                                                 \
  }

  // iters 0..31 (side0): K-step + one RNG cell each, packed 8 cells/dword
  for (int c8 = 0; c8 < 4; c8++) {
    unsigned int zacc = 0;
#pragma unroll
    for (int sub = 0; sub < 8; sub++) {
      const int it = c8 * 8 + sub;
      KSTEP(gA0s0, gA1s0, it * 32, it * 32);
      CELL_RNG(it);
    }
    zLDS[c8 * 256 + t] = zacc;
  }
  // iters 32..39 (side0), no RNG
  for (int it = 32; it < 40; it++) KSTEP(gA0s0, gA1s0, it * 32, it * 32);
  // iters 40..79 (side1), no RNG
  for (int it = 40; it < 80; it++) KSTEP(gA0s1, gA1s1, (it - 40) * 32, it * 32);
#undef KSTEP
#undef CELL_RNG

  // ---- epilogue: relu+bias, apply mask counts, 3-head dot, row reduction ----
  unsigned int zq[4];
#pragma unroll
  for (int c = 0; c < 4; c++) zq[c] = zLDS[c * 256 + t];

  float w0v[2], w1v[2], w2v[2], bcv[2];
#pragma unroll
  for (int j = 0; j < 2; j++) {
    const int n = n0 + wc * 32 + j * 16 + nn;
    w0v[j] = W0[n]; w1v[j] = W1[n]; w2v[j] = W2[n]; bcv[j] = bc[n];
  }

  float* const dst = (wc == 0) ? rowsumA : rowsumB;
#pragma unroll
  for (int i = 0; i < 4; i++) {
#pragma unroll
    for (int rg = 0; rg < 4; rg++) {
      float s0 = 0.f, s1 = 0.f, s2 = 0.f;
#pragma unroll
      for (int j = 0; j < 2; j++) {
        const int idx = i * 8 + j * 4 + rg;
        const unsigned int z5 = (zq[idx >> 3] >> (4 * (idx & 7))) & 7u;
        float v = acc[i][j][rg] + bcv[j];
        v = v > 0.f ? v : 0.f;
        const float tx = v * (float)(5 - (int)z5);
        s0 += tx * w0v[j]; s1 += tx * w1v[j]; s2 += tx * w2v[j];
      }
      // 16-lane (nn) reduction: lanes share the output row
#pragma unroll
      for (int off = 1; off < 16; off <<= 1) {
        s0 += __shfl_xor(s0, off);
        s1 += __shfl_xor(s1, off);
        s2 += __shfl_xor(s2, off);
      }
      if (nn == 0) {
        const int row = wr * 64 + i * 16 + mq + rg;
        dst[row * 3 + 0] = s0; dst[row * 3 + 1] = s1; dst[row * 3 + 2] = s2;
      }
    }
  }
  __syncthreads();

  // ---- per-patient-fragment atomics ----
  if (t < 128) {
    const int pr = p0 + t;
    const int rem = pr % 6;
    if (t == 0 || rem == 0) {
      int nrows = 6 - rem;
      if (nrows > 128 - t) nrows = 128 - t;
      float a0 = 0.f, a1 = 0.f, a2 = 0.f;
      for (int k2 = 0; k2 < nrows; k2++) {
        a0 += rowsumA[(t + k2) * 3 + 0] + rowsumB[(t + k2) * 3 + 0];
        a1 += rowsumA[(t + k2) * 3 + 1] + rowsumB[(t + k2) * 3 + 1];
        a2 += rowsumA[(t + k2) * 3 + 2] + rowsumB[(t + k2) * 3 + 2];
      }
      const int pat = pr / 6;
      atomicAdd(&out[pat * 3 + 0], a0 * (1.0f / 15.0f));
      atomicAdd(&out[pat * 3 + 1], a1 * (1.0f / 15.0f));
      atomicAdd(&out[pat * 3 + 2], a2 * (1.0f / 15.0f));
    }
  }
}

extern "C" void kernel_launch(void* const* d_in, const int* in_sizes, int n_in,
                              void* d_out, int out_size, void* d_ws, size_t ws_size,
                              hipStream_t stream) {
  const float* x  = (const float*)d_in[0];
  // d_in[1] = ids2 (int32): repeat(arange(B),6) -> hardcoded pat = p/6 mapping
  const float* Wc = (const float*)d_in[2];
  const float* bc = (const float*)d_in[3];
  const float* W0 = (const float*)d_in[4];
  const float* b0 = (const float*)d_in[5];
  const float* W1 = (const float*)d_in[6];
  const float* b1 = (const float*)d_in[7];
  const float* W2 = (const float*)d_in[8];
  const float* b2 = (const float*)d_in[9];
  float* out = (float*)d_out;

  char* ws = (char*)d_ws;
  unsigned short* xb = (unsigned short*)ws;                       // 20,971,520 B
  unsigned short* Wb = (unsigned short*)(ws + 20971520);          //  6,553,600 B

  prep<<<23064, 256, 0, stream>>>(x, xb, Wc, Wb, b0, b1, b2, out);
  gemm_relu_dot<<<1920, 256, 0, stream>>>(xb, Wb, bc, W0, W1, W2, out);
}